// Round 1
// baseline (14070.705 us; speedup 1.0000x reference)
//
#include <hip/hip_runtime.h>
#include <hip/hip_bf16.h>

// Model config
#define Lc 2
#define Hc 1024
#define NHc 16
#define HDc 64
#define FFc 4096
#define Ec 8
#define Kc 2
#define Vc 32000
#define Sc 2048
#define EPSc 1e-5f

#define TM 64
#define TN 64
#define TKK 32

// ---------------- embedding ----------------
__global__ __launch_bounds__(256) void k_embed(const int* __restrict__ idx,
    const float* __restrict__ tok, const float* __restrict__ pos,
    float* __restrict__ x) {
  int t = blockIdx.x;
  int id = idx[t];
  for (int i = threadIdx.x; i < Hc; i += 256)
    x[t * Hc + i] = tok[(size_t)id * Hc + i] + pos[t * Hc + i];
}

// ---------------- layernorm (row of 1024, block=256) ----------------
__global__ __launch_bounds__(256) void k_ln(const float* __restrict__ x,
    const float* __restrict__ g, const float* __restrict__ b,
    float* __restrict__ o) {
  int row = blockIdx.x;
  int tid = threadIdx.x;
  const float* xr = x + (size_t)row * Hc;
  float v[4];
  float s = 0.f;
#pragma unroll
  for (int i = 0; i < 4; i++) { v[i] = xr[tid + 256 * i]; s += v[i]; }
  __shared__ float red[256];
  red[tid] = s; __syncthreads();
  for (int st = 128; st > 0; st >>= 1) {
    if (tid < st) red[tid] += red[tid + st];
    __syncthreads();
  }
  float mu = red[0] * (1.0f / Hc);
  __syncthreads();
  float s2 = 0.f;
#pragma unroll
  for (int i = 0; i < 4; i++) { float d = v[i] - mu; s2 += d * d; }
  red[tid] = s2; __syncthreads();
  for (int st = 128; st > 0; st >>= 1) {
    if (tid < st) red[tid] += red[tid + st];
    __syncthreads();
  }
  float rs = rsqrtf(red[0] * (1.0f / Hc) + EPSc);
  float* orow = o + (size_t)row * Hc;
#pragma unroll
  for (int i = 0; i < 4; i++) {
    int c = tid + 256 * i;
    orow[c] = (v[i] - mu) * rs * g[c] + b[c];
  }
}

// ---------------- generic NT GEMM: C = A[M,K] @ B[N,K]^T (+bias)(+resid) ----------------
__global__ __launch_bounds__(256) void k_gemm_nt(
    const float* __restrict__ A, const float* __restrict__ B,
    const float* __restrict__ bias, const float* __restrict__ resid,
    float* __restrict__ C, int M, int N, int K) {
  __shared__ float As[TKK][TM + 4];
  __shared__ float Bs[TKK][TN + 4];
  int m0 = blockIdx.x * TM, n0 = blockIdx.y * TN;
  int tid = threadIdx.x;
  int tx = tid & 15, ty = tid >> 4;
  int lrow = tid >> 3, lk = (tid & 7) * 4;
  float acc[4][4] = {};
  for (int k0 = 0; k0 < K; k0 += TKK) {
#pragma unroll
    for (int p = 0; p < 2; p++) {
      int r = lrow + 32 * p;
      float4 av = *(const float4*)&A[(size_t)(m0 + r) * K + k0 + lk];
      As[lk + 0][r] = av.x; As[lk + 1][r] = av.y;
      As[lk + 2][r] = av.z; As[lk + 3][r] = av.w;
      float4 bv = *(const float4*)&B[(size_t)(n0 + r) * K + k0 + lk];
      Bs[lk + 0][r] = bv.x; Bs[lk + 1][r] = bv.y;
      Bs[lk + 2][r] = bv.z; Bs[lk + 3][r] = bv.w;
    }
    __syncthreads();
#pragma unroll
    for (int kk = 0; kk < TKK; kk++) {
      float4 a = *(const float4*)&As[kk][ty * 4];
      float4 b = *(const float4*)&Bs[kk][tx * 4];
      const float* ap = (const float*)&a;
      const float* bp = (const float*)&b;
#pragma unroll
      for (int i = 0; i < 4; i++)
#pragma unroll
        for (int j = 0; j < 4; j++) acc[i][j] = fmaf(ap[i], bp[j], acc[i][j]);
    }
    __syncthreads();
  }
#pragma unroll
  for (int i = 0; i < 4; i++) {
    int m = m0 + ty * 4 + i;
    float4 outv;
    float* op = (float*)&outv;
#pragma unroll
    for (int j = 0; j < 4; j++) {
      int n = n0 + tx * 4 + j;
      float v = acc[i][j];
      if (bias) v += bias[n];
      if (resid) v += resid[(size_t)m * N + n];
      op[j] = v;
    }
    *(float4*)&C[(size_t)m * N + n0 + tx * 4] = outv;
  }
}

// ---------------- attention: one wave per (head, query), online softmax ----------------
__global__ __launch_bounds__(256) void k_attn(const float* __restrict__ qkv,
                                              float* __restrict__ ctx) {
  int wave = (blockIdx.x * 256 + threadIdx.x) >> 6;
  int lane = threadIdx.x & 63;
  int h = wave >> 11;          // S = 2048 = 2^11
  int q = wave & (Sc - 1);
  const float scale = 0.125f;  // 1/sqrt(64)
  float ql = qkv[(size_t)q * 3072 + h * 64 + lane] * scale;
  float m = -INFINITY, l = 0.f, acc = 0.f;
  for (int j = 0; j <= q; ++j) {
    float kv = qkv[(size_t)j * 3072 + 1024 + h * 64 + lane];
    float d = ql * kv;
#pragma unroll
    for (int o = 32; o > 0; o >>= 1) d += __shfl_xor(d, o, 64);
    float mn = fmaxf(m, d);
    float ex = __expf(d - mn);
    float alpha = __expf(m - mn);
    float vv = qkv[(size_t)j * 3072 + 2048 + h * 64 + lane];
    acc = acc * alpha + ex * vv;
    l = l * alpha + ex;
    m = mn;
  }
  ctx[(size_t)q * Hc + h * 64 + lane] = acc / l;
}

// ---------------- router: softmax over 8 experts + top-2 + counts ----------------
__global__ __launch_bounds__(256) void k_router(const float* __restrict__ xf,
    const float* __restrict__ rw, int* __restrict__ topi,
    float* __restrict__ topw, int* __restrict__ counts) {
  int t = blockIdx.x;
  int tid = threadIdx.x;
  int e = tid >> 5, l = tid & 31;
  const float* xr = xf + (size_t)t * Hc;
  const float* we = rw + (size_t)e * Hc;
  float s = 0.f;
  for (int hh = l; hh < Hc; hh += 32) s += xr[hh] * we[hh];
  __shared__ float red[256];
  red[tid] = s; __syncthreads();
  for (int st = 16; st > 0; st >>= 1) {
    if (l < st) red[tid] += red[tid + st];
    __syncthreads();
  }
  if (tid == 0) {
    float lg[Ec], pr[Ec];
    float mx = -INFINITY;
    for (int k = 0; k < Ec; k++) { lg[k] = red[k * 32]; mx = fmaxf(mx, lg[k]); }
    float ps = 0.f;
    for (int k = 0; k < Ec; k++) { pr[k] = expf(lg[k] - mx); ps += pr[k]; }
    float inv = 1.0f / ps;
    for (int k = 0; k < Ec; k++) pr[k] *= inv;
    int i1 = 0;
    for (int k = 1; k < Ec; k++) if (pr[k] > pr[i1]) i1 = k;
    int i2 = (i1 == 0) ? 1 : 0;
    for (int k = 0; k < Ec; k++)
      if (k != i1 && pr[k] > pr[i2]) i2 = k;
    topi[2 * t] = i1; topi[2 * t + 1] = i2;
    topw[2 * t] = pr[i1]; topw[2 * t + 1] = pr[i2];
    atomicAdd(&counts[i1], 1);
    atomicAdd(&counts[i2], 1);
  }
}

__global__ void k_offs(const int* __restrict__ counts, int* __restrict__ offs) {
  int acc = 0;
  for (int e = 0; e < Ec; e++) { offs[e] = acc; acc += counts[e]; }
}

__global__ __launch_bounds__(256) void k_scatter(const int* __restrict__ topi,
    const float* __restrict__ topw, const int* __restrict__ offs,
    int* __restrict__ cursor, int* __restrict__ elist,
    float* __restrict__ ecoef) {
  int t = blockIdx.x * 256 + threadIdx.x;
  if (t >= Sc) return;
#pragma unroll
  for (int s = 0; s < Kc; s++) {
    int e = topi[2 * t + s];
    int p = atomicAdd(&cursor[e], 1);
    int gslot = offs[e] + p;
    elist[gslot] = t;
    ecoef[gslot] = topw[2 * t + s];
  }
}

// ---------------- MoE GEMM1: h1[slot,f] = gelu(x[tok[slot],:] @ w1[e][:,f]) ----------------
__global__ __launch_bounds__(256) void k_moe_gemm1(
    const float* __restrict__ X, const float* __restrict__ W1,
    const int* __restrict__ elist, const int* __restrict__ counts,
    const int* __restrict__ offs, float* __restrict__ H1) {
  int e = blockIdx.z;
  int cnt = counts[e];
  int m0 = blockIdx.x * TM;
  if (m0 >= cnt) return;
  int n0 = blockIdx.y * TN;
  int off = offs[e];
  const float* B = W1 + (size_t)e * Hc * FFc;
  __shared__ float As[TKK][TM + 4];
  __shared__ float Bs[TKK][TN + 4];
  int tid = threadIdx.x, tx = tid & 15, ty = tid >> 4;
  int lrow = tid >> 3, lk = (tid & 7) * 4;
  int lk2 = tid >> 4, ln4 = (tid & 15) * 4;
  float acc[4][4] = {};
  for (int k0 = 0; k0 < Hc; k0 += TKK) {
#pragma unroll
    for (int p = 0; p < 2; p++) {
      int r = lrow + 32 * p;
      float4 av = make_float4(0.f, 0.f, 0.f, 0.f);
      if (m0 + r < cnt) {
        int tok = elist[off + m0 + r];
        av = *(const float4*)&X[(size_t)tok * Hc + k0 + lk];
      }
      As[lk + 0][r] = av.x; As[lk + 1][r] = av.y;
      As[lk + 2][r] = av.z; As[lk + 3][r] = av.w;
      int k = lk2 + 16 * p;
      *(float4*)&Bs[k][ln4] = *(const float4*)&B[(size_t)(k0 + k) * FFc + n0 + ln4];
    }
    __syncthreads();
#pragma unroll
    for (int kk = 0; kk < TKK; kk++) {
      float4 a = *(const float4*)&As[kk][ty * 4];
      float4 b = *(const float4*)&Bs[kk][tx * 4];
      const float* ap = (const float*)&a;
      const float* bp = (const float*)&b;
#pragma unroll
      for (int i = 0; i < 4; i++)
#pragma unroll
        for (int j = 0; j < 4; j++) acc[i][j] = fmaf(ap[i], bp[j], acc[i][j]);
    }
    __syncthreads();
  }
#pragma unroll
  for (int i = 0; i < 4; i++) {
    int r = m0 + ty * 4 + i;
    if (r < cnt) {
      float4 outv;
      float* op = (float*)&outv;
#pragma unroll
      for (int j = 0; j < 4; j++) {
        float xv = acc[i][j];
        op[j] = 0.5f * xv * (1.0f + erff(xv * 0.70710678118654752f));
      }
      *(float4*)&H1[(size_t)(off + r) * FFc + n0 + tx * 4] = outv;
    }
  }
}

// ---------------- MoE GEMM2: x[tok] += coef * (h1[slot,:] @ w2[e]) ----------------
__global__ __launch_bounds__(256) void k_moe_gemm2(
    const float* __restrict__ H1, const float* __restrict__ W2,
    const int* __restrict__ elist, const float* __restrict__ ecoef,
    const int* __restrict__ counts, const int* __restrict__ offs,
    float* __restrict__ X) {
  int e = blockIdx.z;
  int cnt = counts[e];
  int m0 = blockIdx.x * TM;
  if (m0 >= cnt) return;
  int n0 = blockIdx.y * TN;
  int off = offs[e];
  const float* A = H1 + (size_t)off * FFc;
  const float* B = W2 + (size_t)e * FFc * Hc;
  __shared__ float As[TKK][TM + 4];
  __shared__ float Bs[TKK][TN + 4];
  int tid = threadIdx.x, tx = tid & 15, ty = tid >> 4;
  int lrow = tid >> 3, lk = (tid & 7) * 4;
  int lk2 = tid >> 4, ln4 = (tid & 15) * 4;
  float acc[4][4] = {};
  for (int k0 = 0; k0 < FFc; k0 += TKK) {
#pragma unroll
    for (int p = 0; p < 2; p++) {
      int r = lrow + 32 * p;
      float4 av = make_float4(0.f, 0.f, 0.f, 0.f);
      if (m0 + r < cnt)
        av = *(const float4*)&A[(size_t)(m0 + r) * FFc + k0 + lk];
      As[lk + 0][r] = av.x; As[lk + 1][r] = av.y;
      As[lk + 2][r] = av.z; As[lk + 3][r] = av.w;
      int k = lk2 + 16 * p;
      *(float4*)&Bs[k][ln4] = *(const float4*)&B[(size_t)(k0 + k) * Hc + n0 + ln4];
    }
    __syncthreads();
#pragma unroll
    for (int kk = 0; kk < TKK; kk++) {
      float4 a = *(const float4*)&As[kk][ty * 4];
      float4 b = *(const float4*)&Bs[kk][tx * 4];
      const float* ap = (const float*)&a;
      const float* bp = (const float*)&b;
#pragma unroll
      for (int i = 0; i < 4; i++)
#pragma unroll
        for (int j = 0; j < 4; j++) acc[i][j] = fmaf(ap[i], bp[j], acc[i][j]);
    }
    __syncthreads();
  }
#pragma unroll
  for (int i = 0; i < 4; i++) {
    int r = m0 + ty * 4 + i;
    if (r < cnt) {
      int tok = elist[off + r];
      float cf = ecoef[off + r];
#pragma unroll
      for (int j = 0; j < 4; j++)
        atomicAdd(&X[(size_t)tok * Hc + n0 + tx * 4 + j], cf * acc[i][j]);
    }
  }
}

extern "C" void kernel_launch(void* const* d_in, const int* in_sizes, int n_in,
                              void* d_out, int out_size, void* d_ws, size_t ws_size,
                              hipStream_t stream) {
  const int*   idx   = (const int*)d_in[0];
  const float* tok   = (const float*)d_in[1];
  const float* pos   = (const float*)d_in[2];
  const float* ln1g  = (const float*)d_in[3];
  const float* ln1b  = (const float*)d_in[4];
  const float* wqkv  = (const float*)d_in[5];
  const float* bqkv  = (const float*)d_in[6];
  const float* wo    = (const float*)d_in[7];
  const float* bo    = (const float*)d_in[8];
  const float* ln2g  = (const float*)d_in[9];
  const float* ln2b  = (const float*)d_in[10];
  const float* rw    = (const float*)d_in[11];
  const float* w1    = (const float*)d_in[12];
  const float* w2    = (const float*)d_in[13];
  const float* lnfg  = (const float*)d_in[14];
  const float* lnfb  = (const float*)d_in[15];

  float* ws   = (float*)d_ws;
  float* x    = ws;                    // Sc*Hc
  float* lnb  = x + Sc * Hc;           // Sc*Hc
  float* qkv  = lnb + Sc * Hc;         // Sc*3*Hc
  float* ctx  = qkv + Sc * 3 * Hc;     // Sc*Hc
  float* topw  = ctx + Sc * Hc;        // Sc*Kc
  float* ecoef = topw + Sc * Kc;       // Sc*Kc
  int* topi    = (int*)(ecoef + Sc * Kc);  // Sc*Kc
  int* elist   = topi + Sc * Kc;           // Sc*Kc
  int* counts  = elist + Sc * Kc;          // Ec
  int* cursor  = counts + Ec;              // Ec
  int* offs    = cursor + Ec;              // Ec
  float* h1 = (float*)d_out;  // 4096*4096 fp32 scratch inside d_out (262MB); overwritten by LM head at the end

  k_embed<<<Sc, 256, 0, stream>>>(idx, tok, pos, x);
  for (int l = 0; l < Lc; l++) {
    k_ln<<<Sc, 256, 0, stream>>>(x, ln1g + l * Hc, ln1b + l * Hc, lnb);
    k_gemm_nt<<<dim3(Sc / TM, 3 * Hc / TN), 256, 0, stream>>>(
        lnb, wqkv + (size_t)l * 3 * Hc * Hc, bqkv + l * 3 * Hc, nullptr, qkv,
        Sc, 3 * Hc, Hc);
    k_attn<<<NHc * Sc / 4, 256, 0, stream>>>(qkv, ctx);
    k_gemm_nt<<<dim3(Sc / TM, Hc / TN), 256, 0, stream>>>(
        ctx, wo + (size_t)l * Hc * Hc, bo + l * Hc, x, x, Sc, Hc, Hc);
    k_ln<<<Sc, 256, 0, stream>>>(x, ln2g + l * Hc, ln2b + l * Hc, lnb);
    hipMemsetAsync(counts, 0, 2 * Ec * sizeof(int), stream);
    k_router<<<Sc, 256, 0, stream>>>(lnb, rw + (size_t)l * Ec * Hc, topi, topw, counts);
    k_offs<<<1, 1, 0, stream>>>(counts, offs);
    k_scatter<<<Sc / 256, 256, 0, stream>>>(topi, topw, offs, cursor, elist, ecoef);
    k_moe_gemm1<<<dim3(Sc * Kc / TM, FFc / TN, Ec), 256, 0, stream>>>(
        lnb, w1 + (size_t)l * Ec * Hc * FFc, elist, counts, offs, h1);
    k_moe_gemm2<<<dim3(Sc * Kc / TM, Hc / TN, Ec), 256, 0, stream>>>(
        h1, w2 + (size_t)l * Ec * FFc * Hc, elist, ecoef, counts, offs, x);
  }
  k_ln<<<Sc, 256, 0, stream>>>(x, lnfg, lnfb, lnb);
  k_gemm_nt<<<dim3(Sc / TM, Vc / TN), 256, 0, stream>>>(
      lnb, tok, nullptr, nullptr, (float*)d_out, Sc, Vc, Hc);
}